// Round 6
// baseline (401.009 us; speedup 1.0000x reference)
//
#include <hip/hip_runtime.h>
#include <hip/hip_bf16.h>
#include <math.h>

#define B_ 512
#define N_ 32
#define D_ 300
#define R_ 6
#define E_ 256
#define NG_ 50000
#define NS_ 25000

#define KTOT 2100      // 6*300 (Wrel) + 300 (W0)
#define YLD  2112      // Y bf16 leading dim (33*64)
#define XLD  320       // X0H bf16 leading dim (5*64)
#define PLD  304       // k1b partial leading dim (fp32)
#define NCBG 196       // ceil(50000/256) col-blocks (BN=256)
#define NCBS 98        // ceil(25000/256)
#define NPG  784       // NCBG*4 wave-slices per row
#define NPS  392       // NCBS*4

typedef __attribute__((ext_vector_type(8))) short short8;
typedef __attribute__((ext_vector_type(4))) float f32x4;

__device__ __forceinline__ unsigned short f2bf(float f) {
  __hip_bfloat16 h = __float2bfloat16(f);
  return *reinterpret_cast<unsigned short*>(&h);
}

__device__ __forceinline__ void gload_lds16(const unsigned short* g, unsigned short* l) {
  __builtin_amdgcn_global_load_lds(
      (const __attribute__((address_space(1))) void*)g,
      (__attribute__((address_space(3))) void*)l,
      16, 0, 0);
}

// ---------------- K1a: collapse graph to Y[b, 2112] bf16 (zero k-pad) ----------------
__global__ __launch_bounds__(256) void k1a_coef_y(
    const float* __restrict__ x, const int* __restrict__ ei,
    const int* __restrict__ et, unsigned short* __restrict__ Y)
{
  int b = blockIdx.x;
  int tid = threadIdx.x;
  __shared__ int srcs[E_], dsts[E_], ets[E_];
  __shared__ int degc[R_*N_];
  __shared__ float coef[R_*N_];

  srcs[tid] = ei[b*2*E_ + tid];
  dsts[tid] = ei[b*2*E_ + E_ + tid];
  ets[tid]  = et[b*E_ + tid];
  if (tid < R_*N_) { degc[tid] = 0; coef[tid] = 0.0f; }
  __syncthreads();

  atomicAdd(&degc[ets[tid]*N_ + dsts[tid]], 1);
  __syncthreads();

  if (dsts[tid] == 0) {
    int r = ets[tid];
    float ds = 1.0f + (float)degc[r*N_ + srcs[tid]];
    float dd = 1.0f + (float)degc[r*N_ + 0];
    atomicAdd(&coef[r*N_ + srcs[tid]], rsqrtf(ds*dd));
  }
  if (tid < R_) {
    atomicAdd(&coef[tid*N_ + 0], 1.0f/(1.0f + (float)degc[tid*N_]));
  }
  __syncthreads();

  const float* xb = x + (size_t)b*N_*D_;
  unsigned short* Yb = Y + (size_t)b*YLD;
  for (int k = tid; k < D_; k += 256) {
    #pragma unroll
    for (int r = 0; r < R_; ++r) {
      float acc = 0.0f;
      for (int n = 0; n < N_; ++n) {
        float c = coef[r*N_ + n];          // uniform across threads
        if (c != 0.0f) acc += c * xb[n*D_ + k];
      }
      Yb[r*D_ + k] = f2bf(acc);
    }
    Yb[6*D_ + k] = f2bf(xb[k]);            // x[b,0,:] for the W0 term
  }
  if (tid < YLD - KTOT) Yb[KTOT + tid] = 0;
}

// ---------------- k1b gemm (round-5 proven): BM=256, BN=64, BK=64 ----------------
__global__ __launch_bounds__(256, 3) void gemm_k1b(
    const unsigned short* __restrict__ A, int lda,
    const float* __restrict__ B0, const float* __restrict__ B1,
    float* __restrict__ P1, int nz)
{
  __shared__ unsigned short As[256*64];
  __shared__ unsigned short Bs[64*80];

  const int tid  = threadIdx.x;
  const int lane = tid & 63, wid = tid >> 6;
  const int lr = lane & 15, lg = lane >> 4;

  int id = blockIdx.x;          // 2 mb * 5 cb * nz
  int mb = id & 1; id >>= 1;
  int cb = id % 5, z = id / 5;
  const int m0 = mb*256, c0 = cb*64;
  const int ksplit = 6*D_;

  const int r8 = lane >> 3, sl = lane & 7;
  const int c_l = tid & 63, ob = tid >> 6;
  const int gcol = c0 + c_l;
  const bool cok = (gcol < D_);

  f32x4 acc[4][4];
  #pragma unroll
  for (int a = 0; a < 4; ++a)
    #pragma unroll
    for (int b = 0; b < 4; ++b) acc[a][b] = (f32x4){0.f,0.f,0.f,0.f};

  for (int t = z; t < 33; t += nz) {
    const int kt = t * 64;
    __syncthreads();

    #pragma unroll
    for (int i = 0; i < 8; ++i) {
      int row_l = wid*64 + i*8 + r8;
      int sslot = sl ^ (row_l & 7);
      gload_lds16(A + (size_t)(m0 + row_l)*lda + kt + sslot*8, &As[(wid*64 + i*8)*64]);
    }

    #pragma unroll
    for (int it = 0; it < 2; ++it) {
      int o  = ob + it*4;
      int kb = kt + o*8;
      unsigned short u[8];
      #pragma unroll
      for (int j = 0; j < 8; ++j) {
        int k = kb + j;
        float v = 0.f;
        if (cok && k < KTOT)
          v = (k < ksplit) ? B0[(size_t)k*D_ + gcol]
                           : B1[(size_t)(k - ksplit)*D_ + gcol];
        u[j] = f2bf(v);
      }
      *reinterpret_cast<short8*>(&Bs[c_l*80 + ((o ^ (c_l & 7)) << 3)]) =
          *reinterpret_cast<const short8*>(u);
    }

    __syncthreads();

    #pragma unroll
    for (int kk = 0; kk < 2; ++kk) {
      const int q = kk*4 + lg;
      short8 bfr[4];
      #pragma unroll
      for (int b = 0; b < 4; ++b) {
        int col = b*16 + lr;
        bfr[b] = *reinterpret_cast<const short8*>(&Bs[col*80 + ((q ^ (col & 7)) << 3)]);
      }
      #pragma unroll
      for (int a = 0; a < 4; ++a) {
        int row = wid*64 + a*16 + lr;
        short8 af = *reinterpret_cast<const short8*>(&As[row*64 + ((q ^ (row & 7)) << 3)]);
        #pragma unroll
        for (int b = 0; b < 4; ++b)
          acc[a][b] = __builtin_amdgcn_mfma_f32_16x16x32_bf16(af, bfr[b], acc[a][b], 0, 0, 0);
      }
    }
  }

  float* o = P1 + (size_t)z * (size_t)B_ * PLD;
  #pragma unroll
  for (int a = 0; a < 4; ++a) {
    int row = m0 + wid*64 + a*16 + lg*4;
    #pragma unroll
    for (int b = 0; b < 4; ++b) {
      int col = c0 + b*16 + lr;
      if (col < D_) {
        #pragma unroll
        for (int i = 0; i < 4; ++i)
          o[(size_t)(row + i)*PLD + col] = acc[a][b][i];
      }
    }
  }
}

// ---------------- gemm5: heads. BM=128, BN=256, BK=64, 4 waves n-split ----------------
// Writes logits+bias to out (1KB contiguous per row per block) and per-wave-slice
// (max, sumexp) stats to part[row][cb*4 + wn].
__global__ __launch_bounds__(256, 3) void gemm5(
    const unsigned short* __restrict__ X0H,
    const float* __restrict__ Wg, const float* __restrict__ bg,
    const float* __restrict__ Ws, const float* __restrict__ bs,
    float* __restrict__ out, float2* __restrict__ Pg, float2* __restrict__ Ps)
{
  __shared__ unsigned short As[128*64];   // 16 KB
  __shared__ unsigned short Bs[256*64];   // 32 KB

  // bijective XCD-chunk swizzle (grid = 1176 = 8*147)
  int id = blockIdx.x;
  { int q = gridDim.x >> 3; id = (id & 7)*q + (id >> 3); }
  const bool hg = (id < 4*NCBG);
  const int hid = hg ? id : id - 4*NCBG;
  const int mb = hid & 3, cb = hid >> 2;   // mb fastest: W slice L2-shared
  const int m0 = mb*128, c0 = cb*256;

  const float* W   = hg ? Wg : Ws;
  const float* bia = hg ? bg : bs;
  const int C      = hg ? NG_ : NS_;
  float* outp      = hg ? out : out + (size_t)B_*NG_;
  float2* part     = hg ? Pg : Ps;
  const int ldpart = hg ? NPG : NPS;

  const int tid  = threadIdx.x;
  const int lane = tid & 63, wn = tid >> 6;
  const int lr = lane & 15, lg = lane >> 4;
  const int r8 = lane >> 3, sl = lane & 7;

  const int gcol = c0 + tid;               // B gather: one col per thread
  const bool cok = (gcol < C);

  f32x4 acc[8][4];
  #pragma unroll
  for (int a = 0; a < 8; ++a)
    #pragma unroll
    for (int b = 0; b < 4; ++b) acc[a][b] = (f32x4){0.f,0.f,0.f,0.f};

  for (int t = 0; t < 5; ++t) {
    const int kt = t * 64;
    __syncthreads();

    // A: 128 rows x 64 k via 16 DMAs (4 per wave), pre-swizzled source
    #pragma unroll
    for (int i = 0; i < 4; ++i) {
      int row_l = wn*32 + i*8 + r8;
      int sslot = sl ^ (row_l & 7);
      gload_lds16(X0H + (size_t)(m0 + row_l)*XLD + kt + sslot*8, &As[(wn*32 + i*8)*64]);
    }

    // B: 8 octets (64 k) for this thread's column, swizzled b128 writes
    #pragma unroll
    for (int o = 0; o < 8; ++o) {
      int kb = kt + o*8;
      unsigned short u[8];
      #pragma unroll
      for (int j = 0; j < 8; ++j) {
        int k = kb + j;
        float v = (cok && k < D_) ? W[(size_t)k*C + gcol] : 0.f;
        u[j] = f2bf(v);
      }
      *reinterpret_cast<short8*>(&Bs[tid*64 + ((o ^ (tid & 7)) << 3)]) =
          *reinterpret_cast<const short8*>(u);
    }

    __syncthreads();

    #pragma unroll
    for (int kk = 0; kk < 2; ++kk) {
      const int q = kk*4 + lg;
      short8 bfr[4];
      #pragma unroll
      for (int b = 0; b < 4; ++b) {
        int col = wn*64 + b*16 + lr;
        bfr[b] = *reinterpret_cast<const short8*>(&Bs[col*64 + ((q ^ (col & 7)) << 3)]);
      }
      #pragma unroll
      for (int a = 0; a < 8; ++a) {
        int row = a*16 + lr;
        short8 af = *reinterpret_cast<const short8*>(&As[row*64 + ((q ^ (row & 7)) << 3)]);
        #pragma unroll
        for (int b = 0; b < 4; ++b)
          acc[a][b] = __builtin_amdgcn_mfma_f32_16x16x32_bf16(af, bfr[b], acc[a][b], 0, 0, 0);
      }
    }
  }

  // ---- epilogue: logits + bias -> out, per-slice (max, sumexp) -> part ----
  float bv[4]; bool okc[4];
  #pragma unroll
  for (int b = 0; b < 4; ++b) {
    int col = c0 + wn*64 + b*16 + lr;
    okc[b] = (col < C);
    bv[b] = okc[b] ? bia[col] : 0.f;
  }
  #pragma unroll
  for (int a = 0; a < 8; ++a) {
    #pragma unroll
    for (int i = 0; i < 4; ++i) {
      int row = m0 + a*16 + lg*4 + i;
      float v[4], mx = -3.0e38f;
      #pragma unroll
      for (int b = 0; b < 4; ++b) {
        v[b] = okc[b] ? (acc[a][b][i] + bv[b]) : -3.0e38f;
        mx = fmaxf(mx, v[b]);
      }
      #pragma unroll
      for (int b = 0; b < 4; ++b)
        if (okc[b]) outp[(size_t)row*C + c0 + wn*64 + b*16 + lr] = v[b];
      #pragma unroll
      for (int off = 1; off < 16; off <<= 1) mx = fmaxf(mx, __shfl_xor(mx, off));
      float s = 0.f;
      #pragma unroll
      for (int b = 0; b < 4; ++b) s += __expf(v[b] - mx);
      #pragma unroll
      for (int off = 1; off < 16; off <<= 1) s += __shfl_xor(s, off);
      if (lr == 0) part[(size_t)row*ldpart + cb*4 + wn] = make_float2(mx, s);
    }
  }
}

// ---------------- K1c: reduce z-partials, leaky, emit bf16 X0H [512][320] ----------------
__global__ __launch_bounds__(256) void k1c_reduce(
    const float* __restrict__ part, int nz, unsigned short* __restrict__ X0Hbf)
{
  int idx = blockIdx.x*256 + threadIdx.x;
  if (idx >= B_*XLD) return;
  int m = idx / XLD, c = idx % XLD;
  float v = 0.f;
  if (c < D_) {
    for (int zz = 0; zz < nz; ++zz) v += part[(size_t)zz*B_*PLD + (size_t)m*PLD + c];
    v = (v >= 0.f) ? v : 0.1f*v;
  }
  X0Hbf[idx] = f2bf(v);
}

// ---------------- K5: combine (m,s) partials -> lse[1024] ----------------
__global__ __launch_bounds__(256) void k5_lse(
    const float2* __restrict__ pg, const float2* __restrict__ ps,
    float* __restrict__ lse)
{
  int row = blockIdx.x;
  const float2* p; int n;
  if (row < B_) { p = pg + (size_t)row*NPG; n = NPG; }
  else          { p = ps + (size_t)(row - B_)*NPS; n = NPS; }
  float m = -3.0e38f, s = 0.f;
  for (int i = threadIdx.x; i < n; i += 256) {
    float2 v = p[i];
    float mn = fmaxf(m, v.x);
    s = s*__expf(m - mn) + v.y*__expf(v.x - mn);
    m = mn;
  }
  #pragma unroll
  for (int off = 1; off < 64; off <<= 1) {
    float m2 = __shfl_xor(m, off), s2 = __shfl_xor(s, off);
    float mn = fmaxf(m, m2);
    s = s*__expf(m - mn) + s2*__expf(m2 - mn);
    m = mn;
  }
  __shared__ float ms[4], ss2[4];
  int w = threadIdx.x >> 6;
  if ((threadIdx.x & 63) == 0) { ms[w] = m; ss2[w] = s; }
  __syncthreads();
  if (threadIdx.x == 0) {
    float M = ms[0], S = ss2[0];
    #pragma unroll
    for (int ww = 1; ww < 4; ++ww) {
      float mn = fmaxf(M, ms[ww]);
      S = S*__expf(M - mn) + ss2[ww]*__expf(ms[ww] - mn);
      M = mn;
    }
    lse[row] = M + __logf(S);
  }
}

// ---------------- K4: out -= lse[row], float4 ----------------
__global__ void k4_sub(float* __restrict__ out, const float* __restrict__ lse)
{
  const size_t g4 = (size_t)B_*NG_/4;
  const size_t total4 = g4 + (size_t)B_*NS_/4;
  size_t stride = (size_t)gridDim.x * blockDim.x;
  for (size_t i4 = (size_t)blockIdx.x*blockDim.x + threadIdx.x; i4 < total4; i4 += stride) {
    int row;
    if (i4 < g4) row = (int)(i4 / (NG_/4));
    else         row = B_ + (int)((i4 - g4) / (NS_/4));
    float l = lse[row];
    float4 v = reinterpret_cast<float4*>(out)[i4];
    v.x -= l; v.y -= l; v.z -= l; v.w -= l;
    reinterpret_cast<float4*>(out)[i4] = v;
  }
}

// =====================================================================
extern "C" void kernel_launch(void* const* d_in, const int* in_sizes, int n_in,
                              void* d_out, int out_size, void* d_ws, size_t ws_size,
                              hipStream_t stream)
{
  const float* x    = (const float*)d_in[0];
  const int*   ei   = (const int*)  d_in[1];
  const int*   et   = (const int*)  d_in[2];
  const float* Wrel = (const float*)d_in[3];
  const float* W0   = (const float*)d_in[4];
  const float* Wg   = (const float*)d_in[5];
  const float* bg   = (const float*)d_in[6];
  const float* Ws   = (const float*)d_in[7];
  const float* bs   = (const float*)d_in[8];
  float* out = (float*)d_out;

  // ws layout (bytes): Ybf | X0H | P1 | Pg | Ps | LSE   (~12.3 MB)
  char* p = (char*)d_ws;
  unsigned short* Ybf = (unsigned short*)p;  p += (size_t)B_*YLD*2;
  unsigned short* X0H = (unsigned short*)p;  p += (size_t)B_*XLD*2;
  float*  P1  = (float*)p;                   p += (size_t)8*B_*PLD*4;
  float2* Pg  = (float2*)p;                  p += (size_t)B_*NPG*8;
  float2* Ps  = (float2*)p;                  p += (size_t)B_*NPS*8;
  float*  LSE = (float*)p;

  k1a_coef_y<<<B_, 256, 0, stream>>>(x, ei, et, Ybf);

  // k1b: P1[z] = Y @ [Wrel;W0] partials (z-split over 33 K-tiles)
  gemm_k1b<<<2*5*8, 256, 0, stream>>>(Ybf, YLD, Wrel, W0, P1, 8);
  k1c_reduce<<<(B_*XLD + 255)/256, 256, 0, stream>>>(P1, 8, X0H);

  // heads: logits (+bias) -> out, per-wave-slice (max,sumexp) -> Pg/Ps
  gemm5<<<4*(NCBG + NCBS), 256, 0, stream>>>(X0H, Wg, bg, Ws, bs, out, Pg, Ps);

  k5_lse<<<2*B_, 256, 0, stream>>>(Pg, Ps, LSE);
  k4_sub<<<2048, 256, 0, stream>>>(out, LSE);
}

// Round 7
// 324.642 us; speedup vs baseline: 1.2352x; 1.2352x over previous
//
#include <hip/hip_runtime.h>
#include <hip/hip_bf16.h>
#include <math.h>

#define B_ 512
#define N_ 32
#define D_ 300
#define R_ 6
#define E_ 256
#define NG_ 50000
#define NS_ 25000

#define KTOT 2100      // 6*300 (Wrel) + 300 (W0)
#define YLD  2112      // Y bf16 leading dim (33*64)
#define XLD  320       // X0H bf16 leading dim (5*64)
#define PLD  304       // k1b partial leading dim (fp32)
#define NCBG 782       // ceil(50000/64)
#define NCBS 391       // ceil(25000/64)

typedef __attribute__((ext_vector_type(8))) short short8;
typedef __attribute__((ext_vector_type(4))) float f32x4;

__device__ __forceinline__ unsigned short f2bf(float f) {
  __hip_bfloat16 h = __float2bfloat16(f);
  return *reinterpret_cast<unsigned short*>(&h);
}

__device__ __forceinline__ void gload_lds16(const unsigned short* g, unsigned short* l) {
  __builtin_amdgcn_global_load_lds(
      (const __attribute__((address_space(1))) void*)g,
      (__attribute__((address_space(3))) void*)l,
      16, 0, 0);
}

// ---------------- K1a: collapse graph to Y[b, 2112] bf16 (zero k-pad) ----------------
__global__ __launch_bounds__(256) void k1a_coef_y(
    const float* __restrict__ x, const int* __restrict__ ei,
    const int* __restrict__ et, unsigned short* __restrict__ Y)
{
  int b = blockIdx.x;
  int tid = threadIdx.x;
  __shared__ int srcs[E_], dsts[E_], ets[E_];
  __shared__ int degc[R_*N_];
  __shared__ float coef[R_*N_];

  srcs[tid] = ei[b*2*E_ + tid];
  dsts[tid] = ei[b*2*E_ + E_ + tid];
  ets[tid]  = et[b*E_ + tid];
  if (tid < R_*N_) { degc[tid] = 0; coef[tid] = 0.0f; }
  __syncthreads();

  atomicAdd(&degc[ets[tid]*N_ + dsts[tid]], 1);
  __syncthreads();

  if (dsts[tid] == 0) {
    int r = ets[tid];
    float ds = 1.0f + (float)degc[r*N_ + srcs[tid]];
    float dd = 1.0f + (float)degc[r*N_ + 0];
    atomicAdd(&coef[r*N_ + srcs[tid]], rsqrtf(ds*dd));
  }
  if (tid < R_) {
    atomicAdd(&coef[tid*N_ + 0], 1.0f/(1.0f + (float)degc[tid*N_]));
  }
  __syncthreads();

  const float* xb = x + (size_t)b*N_*D_;
  unsigned short* Yb = Y + (size_t)b*YLD;
  for (int k = tid; k < D_; k += 256) {
    #pragma unroll
    for (int r = 0; r < R_; ++r) {
      float acc = 0.0f;
      for (int n = 0; n < N_; ++n) {
        float c = coef[r*N_ + n];          // uniform across threads
        if (c != 0.0f) acc += c * xb[n*D_ + k];
      }
      Yb[r*D_ + k] = f2bf(acc);
    }
    Yb[6*D_ + k] = f2bf(xb[k]);            // x[b,0,:] for the W0 term
  }
  if (tid < YLD - KTOT) Yb[KTOT + tid] = 0;
}

// ---------------- k1b gemm (round-5 proven): BM=256, BN=64, BK=64 ----------------
__global__ __launch_bounds__(256, 3) void gemm_k1b(
    const unsigned short* __restrict__ A, int lda,
    const float* __restrict__ B0, const float* __restrict__ B1,
    float* __restrict__ P1, int nz)
{
  __shared__ unsigned short As[256*64];
  __shared__ unsigned short Bs[64*80];

  const int tid  = threadIdx.x;
  const int lane = tid & 63, wid = tid >> 6;
  const int lr = lane & 15, lg = lane >> 4;

  int id = blockIdx.x;          // 2 mb * 5 cb * nz
  int mb = id & 1; id >>= 1;
  int cb = id % 5, z = id / 5;
  const int m0 = mb*256, c0 = cb*64;
  const int ksplit = 6*D_;

  const int r8 = lane >> 3, sl = lane & 7;
  const int c_l = tid & 63, ob = tid >> 6;
  const int gcol = c0 + c_l;
  const bool cok = (gcol < D_);

  f32x4 acc[4][4];
  #pragma unroll
  for (int a = 0; a < 4; ++a)
    #pragma unroll
    for (int b = 0; b < 4; ++b) acc[a][b] = (f32x4){0.f,0.f,0.f,0.f};

  for (int t = z; t < 33; t += nz) {
    const int kt = t * 64;
    __syncthreads();

    #pragma unroll
    for (int i = 0; i < 8; ++i) {
      int row_l = wid*64 + i*8 + r8;
      int sslot = sl ^ (row_l & 7);
      gload_lds16(A + (size_t)(m0 + row_l)*lda + kt + sslot*8, &As[(wid*64 + i*8)*64]);
    }

    #pragma unroll
    for (int it = 0; it < 2; ++it) {
      int o  = ob + it*4;
      int kb = kt + o*8;
      unsigned short u[8];
      #pragma unroll
      for (int j = 0; j < 8; ++j) {
        int k = kb + j;
        float v = 0.f;
        if (cok && k < KTOT)
          v = (k < ksplit) ? B0[(size_t)k*D_ + gcol]
                           : B1[(size_t)(k - ksplit)*D_ + gcol];
        u[j] = f2bf(v);
      }
      *reinterpret_cast<short8*>(&Bs[c_l*80 + ((o ^ (c_l & 7)) << 3)]) =
          *reinterpret_cast<const short8*>(u);
    }

    __syncthreads();

    #pragma unroll
    for (int kk = 0; kk < 2; ++kk) {
      const int q = kk*4 + lg;
      short8 bfr[4];
      #pragma unroll
      for (int b = 0; b < 4; ++b) {
        int col = b*16 + lr;
        bfr[b] = *reinterpret_cast<const short8*>(&Bs[col*80 + ((q ^ (col & 7)) << 3)]);
      }
      #pragma unroll
      for (int a = 0; a < 4; ++a) {
        int row = wid*64 + a*16 + lr;
        short8 af = *reinterpret_cast<const short8*>(&As[row*64 + ((q ^ (row & 7)) << 3)]);
        #pragma unroll
        for (int b = 0; b < 4; ++b)
          acc[a][b] = __builtin_amdgcn_mfma_f32_16x16x32_bf16(af, bfr[b], acc[a][b], 0, 0, 0);
      }
    }
  }

  float* o = P1 + (size_t)z * (size_t)B_ * PLD;
  #pragma unroll
  for (int a = 0; a < 4; ++a) {
    int row = m0 + wid*64 + a*16 + lg*4;
    #pragma unroll
    for (int b = 0; b < 4; ++b) {
      int col = c0 + b*16 + lr;
      if (col < D_) {
        #pragma unroll
        for (int i = 0; i < 4; ++i)
          o[(size_t)(row + i)*PLD + col] = acc[a][b][i];
      }
    }
  }
}

// ---------------- gemm6: heads, T14 register-prefetch pipeline ----------------
// BM=256, BN=64, BK=64, 4 waves (64 rows each). A direct-from-global into regs
// (one tile ahead). B prefetched to regs one tile ahead, staged via swizzled
// ds_write_b128. Raw s_barrier + lgkmcnt-only waits: vmcnt stays in flight.

#define LOADB6(dst, t) do {                                                  \
    _Pragma("unroll")                                                        \
    for (int it = 0; it < 2; ++it) {                                         \
      int o = ob + it*4;                                                     \
      _Pragma("unroll")                                                      \
      for (int j = 0; j < 8; ++j) {                                          \
        int k = (t)*64 + o*8 + j;                                            \
        (dst)[it*8+j] = (cok && k < D_) ? W[(size_t)k*C + gcol] : 0.f;       \
      }                                                                      \
    }                                                                        \
  } while (0)

#define LOADA6(dst, t) do {                                                  \
    _Pragma("unroll")                                                        \
    for (int a = 0; a < 4; ++a)                                              \
      _Pragma("unroll")                                                      \
      for (int kk = 0; kk < 2; ++kk)                                         \
        (dst)[a*2+kk] = *reinterpret_cast<const short8*>(                    \
            &X0H[(size_t)(m0 + wid*64 + a*16 + lr)*XLD + (t)*64 + kk*32 + lg*8]); \
  } while (0)

#define STOREB6(src) do {                                                    \
    _Pragma("unroll")                                                        \
    for (int it = 0; it < 2; ++it) {                                         \
      int o = ob + it*4;                                                     \
      unsigned short u[8];                                                   \
      _Pragma("unroll")                                                      \
      for (int j = 0; j < 8; ++j) u[j] = f2bf((src)[it*8+j]);                \
      *reinterpret_cast<short8*>(&Bs[c_l*72 + ((o ^ (c_l & 7)) << 3)]) =     \
          *reinterpret_cast<const short8*>(u);                               \
    }                                                                        \
  } while (0)

#define MFMA6(AC) do {                                                       \
    _Pragma("unroll")                                                        \
    for (int kk = 0; kk < 2; ++kk) {                                         \
      short8 bfr[4];                                                         \
      _Pragma("unroll")                                                      \
      for (int b = 0; b < 4; ++b) {                                          \
        int col = b*16 + lr;                                                 \
        bfr[b] = *reinterpret_cast<const short8*>(                           \
            &Bs[col*72 + (((kk*4 + lg) ^ (col & 7)) << 3)]);                 \
      }                                                                      \
      _Pragma("unroll")                                                      \
      for (int a = 0; a < 4; ++a)                                            \
        _Pragma("unroll")                                                    \
        for (int b = 0; b < 4; ++b)                                          \
          acc[a][b] = __builtin_amdgcn_mfma_f32_16x16x32_bf16(               \
              (AC)[a*2+kk], bfr[b], acc[a][b], 0, 0, 0);                     \
    }                                                                        \
  } while (0)

#define PHASE6(t, AC, BC, AN, BN_) do {                                      \
    STOREB6(BC);                                                             \
    if ((t) + 1 < 5) { LOADB6(BN_, (t)+1); LOADA6(AN, (t)+1); }              \
    asm volatile("s_waitcnt lgkmcnt(0)" ::: "memory");                       \
    __builtin_amdgcn_s_barrier();                                            \
    __builtin_amdgcn_sched_barrier(0);                                       \
    MFMA6(AC);                                                               \
    asm volatile("s_waitcnt lgkmcnt(0)" ::: "memory");                       \
    __builtin_amdgcn_s_barrier();                                            \
    __builtin_amdgcn_sched_barrier(0);                                       \
  } while (0)

__global__ __launch_bounds__(256, 2) void gemm6(
    const unsigned short* __restrict__ X0H,
    const float* __restrict__ Wg, const float* __restrict__ bg,
    const float* __restrict__ Ws, const float* __restrict__ bs,
    float* __restrict__ out, float2* __restrict__ Pg, float2* __restrict__ Ps)
{
  __shared__ unsigned short Bs[64*72];   // 9 KB

  // bijective XCD-chunked swizzle (m204)
  int nwg = gridDim.x;
  int bid = blockIdx.x;
  int q = nwg >> 3, r = nwg & 7, xcd = bid & 7, loc = bid >> 3;
  int id = (xcd < r ? xcd*(q+1) : r*(q+1) + (xcd-r)*q) + loc;

  const bool hg = (id < 2*NCBG);
  const int hid = hg ? id : id - 2*NCBG;
  const int mb = hid & 1, cb = hid >> 1;   // mb fastest: pair shares W cols in L2
  const int m0 = mb*256, c0 = cb*64;

  const float* W   = hg ? Wg : Ws;
  const float* bia = hg ? bg : bs;
  const int C      = hg ? NG_ : NS_;
  float* outp      = hg ? out : out + (size_t)B_*NG_;
  float2* part     = hg ? Pg : Ps;
  const int ldpart = hg ? NCBG : NCBS;

  const int tid  = threadIdx.x;
  const int lane = tid & 63, wid = tid >> 6;
  const int lr = lane & 15, lg = lane >> 4;
  const int c_l = tid & 63, ob = tid >> 6;
  const int gcol = c0 + c_l;
  const bool cok = (gcol < C);

  f32x4 acc[4][4];
  #pragma unroll
  for (int a = 0; a < 4; ++a)
    #pragma unroll
    for (int b = 0; b < 4; ++b) acc[a][b] = (f32x4){0.f,0.f,0.f,0.f};

  float  bE[16], bO[16];
  short8 aE[8],  aO[8];

  // prologue: tile 0 into E
  LOADB6(bE, 0);
  LOADA6(aE, 0);

  PHASE6(0, aE, bE, aO, bO);
  PHASE6(1, aO, bO, aE, bE);
  PHASE6(2, aE, bE, aO, bO);
  PHASE6(3, aO, bO, aE, bE);
  PHASE6(4, aE, bE, aO, bO);

  // ---- epilogue: logits + bias -> out, per-block (max, sumexp) -> part ----
  float bv[4]; bool okc[4];
  #pragma unroll
  for (int b = 0; b < 4; ++b) {
    int col = c0 + b*16 + lr;
    okc[b] = (col < C);
    bv[b] = okc[b] ? bia[col] : 0.f;
  }
  #pragma unroll
  for (int a = 0; a < 4; ++a) {
    #pragma unroll
    for (int i = 0; i < 4; ++i) {
      int row = m0 + wid*64 + a*16 + lg*4 + i;
      float v[4], mx = -3.0e38f;
      #pragma unroll
      for (int b = 0; b < 4; ++b) {
        v[b] = okc[b] ? (acc[a][b][i] + bv[b]) : -3.0e38f;
        mx = fmaxf(mx, v[b]);
      }
      #pragma unroll
      for (int b = 0; b < 4; ++b)
        if (okc[b]) outp[(size_t)row*C + c0 + b*16 + lr] = v[b];
      #pragma unroll
      for (int off = 1; off < 16; off <<= 1) mx = fmaxf(mx, __shfl_xor(mx, off));
      float s = 0.f;
      #pragma unroll
      for (int b = 0; b < 4; ++b) s += __expf(v[b] - mx);
      #pragma unroll
      for (int off = 1; off < 16; off <<= 1) s += __shfl_xor(s, off);
      if (lr == 0) part[(size_t)row*ldpart + cb] = make_float2(mx, s);
    }
  }
}

// ---------------- K1c: reduce z-partials, leaky, emit bf16 X0H [512][320] ----------------
__global__ __launch_bounds__(256) void k1c_reduce(
    const float* __restrict__ part, int nz, unsigned short* __restrict__ X0Hbf)
{
  int idx = blockIdx.x*256 + threadIdx.x;
  if (idx >= B_*XLD) return;
  int m = idx / XLD, c = idx % XLD;
  float v = 0.f;
  if (c < D_) {
    for (int zz = 0; zz < nz; ++zz) v += part[(size_t)zz*B_*PLD + (size_t)m*PLD + c];
    v = (v >= 0.f) ? v : 0.1f*v;
  }
  X0Hbf[idx] = f2bf(v);
}

// ---------------- K5: combine (m,s) partials -> lse[1024] ----------------
__global__ __launch_bounds__(256) void k5_lse(
    const float2* __restrict__ pg, const float2* __restrict__ ps,
    float* __restrict__ lse)
{
  int row = blockIdx.x;
  const float2* p; int n;
  if (row < B_) { p = pg + (size_t)row*NCBG; n = NCBG; }
  else          { p = ps + (size_t)(row - B_)*NCBS; n = NCBS; }
  float m = -3.0e38f, s = 0.f;
  for (int i = threadIdx.x; i < n; i += 256) {
    float2 v = p[i];
    float mn = fmaxf(m, v.x);
    s = s*__expf(m - mn) + v.y*__expf(v.x - mn);
    m = mn;
  }
  #pragma unroll
  for (int off = 1; off < 64; off <<= 1) {
    float m2 = __shfl_xor(m, off), s2 = __shfl_xor(s, off);
    float mn = fmaxf(m, m2);
    s = s*__expf(m - mn) + s2*__expf(m2 - mn);
    m = mn;
  }
  __shared__ float ms[4], ss2[4];
  int w = threadIdx.x >> 6;
  if ((threadIdx.x & 63) == 0) { ms[w] = m; ss2[w] = s; }
  __syncthreads();
  if (threadIdx.x == 0) {
    float M = ms[0], S = ss2[0];
    #pragma unroll
    for (int ww = 1; ww < 4; ++ww) {
      float mn = fmaxf(M, ms[ww]);
      S = S*__expf(M - mn) + ss2[ww]*__expf(ms[ww] - mn);
      M = mn;
    }
    lse[row] = M + __logf(S);
  }
}

// ---------------- K4: out -= lse[row], float4 ----------------
__global__ void k4_sub(float* __restrict__ out, const float* __restrict__ lse)
{
  const size_t g4 = (size_t)B_*NG_/4;
  const size_t total4 = g4 + (size_t)B_*NS_/4;
  size_t stride = (size_t)gridDim.x * blockDim.x;
  for (size_t i4 = (size_t)blockIdx.x*blockDim.x + threadIdx.x; i4 < total4; i4 += stride) {
    int row;
    if (i4 < g4) row = (int)(i4 / (NG_/4));
    else         row = B_ + (int)((i4 - g4) / (NS_/4));
    float l = lse[row];
    float4 v = reinterpret_cast<float4*>(out)[i4];
    v.x -= l; v.y -= l; v.z -= l; v.w -= l;
    reinterpret_cast<float4*>(out)[i4] = v;
  }
}

// =====================================================================
extern "C" void kernel_launch(void* const* d_in, const int* in_sizes, int n_in,
                              void* d_out, int out_size, void* d_ws, size_t ws_size,
                              hipStream_t stream)
{
  const float* x    = (const float*)d_in[0];
  const int*   ei   = (const int*)  d_in[1];
  const int*   et   = (const int*)  d_in[2];
  const float* Wrel = (const float*)d_in[3];
  const float* W0   = (const float*)d_in[4];
  const float* Wg   = (const float*)d_in[5];
  const float* bg   = (const float*)d_in[6];
  const float* Ws   = (const float*)d_in[7];
  const float* bs   = (const float*)d_in[8];
  float* out = (float*)d_out;

  // ws layout (bytes): Ybf | X0H | P1 | Pg | Ps | LSE   (~12.3 MB)
  char* p = (char*)d_ws;
  unsigned short* Ybf = (unsigned short*)p;  p += (size_t)B_*YLD*2;
  unsigned short* X0H = (unsigned short*)p;  p += (size_t)B_*XLD*2;
  float*  P1  = (float*)p;                   p += (size_t)8*B_*PLD*4;
  float2* Pg  = (float2*)p;                  p += (size_t)B_*NCBG*8;
  float2* Ps  = (float2*)p;                  p += (size_t)B_*NCBS*8;
  float*  LSE = (float*)p;

  k1a_coef_y<<<B_, 256, 0, stream>>>(x, ei, et, Ybf);

  // k1b: P1[z] = Y @ [Wrel;W0] partials (z-split over 33 K-tiles)
  gemm_k1b<<<2*5*8, 256, 0, stream>>>(Ybf, YLD, Wrel, W0, P1, 8);
  k1c_reduce<<<(B_*XLD + 255)/256, 256, 0, stream>>>(P1, 8, X0H);

  // heads: logits (+bias) -> out, per-block (max,sumexp) -> Pg/Ps
  gemm6<<<2*(NCBG + NCBS), 256, 0, stream>>>(X0H, Wg, bg, Ws, bs, out, Pg, Ps);

  k5_lse<<<2*B_, 256, 0, stream>>>(Pg, Ps, LSE);
  k4_sub<<<2048, 256, 0, stream>>>(out, LSE);
}

// Round 8
// 324.340 us; speedup vs baseline: 1.2364x; 1.0009x over previous
//
#include <hip/hip_runtime.h>
#include <hip/hip_bf16.h>
#include <math.h>

#define B_ 512
#define N_ 32
#define D_ 300
#define R_ 6
#define E_ 256
#define NG_ 50000
#define NS_ 25000

#define KTOT 2100      // 6*300 (Wrel) + 300 (W0)
#define YLD  2112      // Y bf16 leading dim (33*64)
#define XLD  320       // X0H bf16 leading dim (5*64)
#define PLD  304       // k1b partial leading dim (fp32)
#define NCBG 782       // ceil(50000/64)
#define NCBS 391       // ceil(25000/64)
#define CPADG (NCBG*64)   // 50048
#define CPADS (NCBS*64)   // 25024
#define NTILE (NCBG+NCBS) // 1173
#define GRP   294         // col-tile groups; grid = 4 mb * 294

typedef __attribute__((ext_vector_type(8))) short short8;
typedef __attribute__((ext_vector_type(4))) float f32x4;

__device__ __forceinline__ unsigned short f2bf(float f) {
  __hip_bfloat16 h = __float2bfloat16(f);
  return *reinterpret_cast<unsigned short*>(&h);
}

__device__ __forceinline__ void gload_lds16(const unsigned short* g, unsigned short* l) {
  __builtin_amdgcn_global_load_lds(
      (const __attribute__((address_space(1))) void*)g,
      (__attribute__((address_space(3))) void*)l,
      16, 0, 0);
}

// ---------------- K1a: collapse graph to Y[b, 2112] bf16 (zero k-pad) ----------------
__global__ __launch_bounds__(256) void k1a_coef_y(
    const float* __restrict__ x, const int* __restrict__ ei,
    const int* __restrict__ et, unsigned short* __restrict__ Y)
{
  int b = blockIdx.x;
  int tid = threadIdx.x;
  __shared__ int srcs[E_], dsts[E_], ets[E_];
  __shared__ int degc[R_*N_];
  __shared__ float coef[R_*N_];

  srcs[tid] = ei[b*2*E_ + tid];
  dsts[tid] = ei[b*2*E_ + E_ + tid];
  ets[tid]  = et[b*E_ + tid];
  if (tid < R_*N_) { degc[tid] = 0; coef[tid] = 0.0f; }
  __syncthreads();

  atomicAdd(&degc[ets[tid]*N_ + dsts[tid]], 1);
  __syncthreads();

  if (dsts[tid] == 0) {
    int r = ets[tid];
    float ds = 1.0f + (float)degc[r*N_ + srcs[tid]];
    float dd = 1.0f + (float)degc[r*N_ + 0];
    atomicAdd(&coef[r*N_ + srcs[tid]], rsqrtf(ds*dd));
  }
  if (tid < R_) {
    atomicAdd(&coef[tid*N_ + 0], 1.0f/(1.0f + (float)degc[tid*N_]));
  }
  __syncthreads();

  const float* xb = x + (size_t)b*N_*D_;
  unsigned short* Yb = Y + (size_t)b*YLD;
  for (int k = tid; k < D_; k += 256) {
    #pragma unroll
    for (int r = 0; r < R_; ++r) {
      float acc = 0.0f;
      for (int n = 0; n < N_; ++n) {
        float c = coef[r*N_ + n];          // uniform across threads
        if (c != 0.0f) acc += c * xb[n*D_ + k];
      }
      Yb[r*D_ + k] = f2bf(acc);
    }
    Yb[6*D_ + k] = f2bf(xb[k]);            // x[b,0,:] for the W0 term
  }
  if (tid < YLD - KTOT) Yb[KTOT + tid] = 0;
}

// ---------------- k1b gemm (round-5 proven): BM=256, BN=64, BK=64 ----------------
__global__ __launch_bounds__(256, 3) void gemm_k1b(
    const unsigned short* __restrict__ A, int lda,
    const float* __restrict__ B0, const float* __restrict__ B1,
    float* __restrict__ P1, int nz)
{
  __shared__ unsigned short As[256*64];
  __shared__ unsigned short Bs[64*80];

  const int tid  = threadIdx.x;
  const int lane = tid & 63, wid = tid >> 6;
  const int lr = lane & 15, lg = lane >> 4;

  int id = blockIdx.x;          // 2 mb * 5 cb * nz
  int mb = id & 1; id >>= 1;
  int cb = id % 5, z = id / 5;
  const int m0 = mb*256, c0 = cb*64;
  const int ksplit = 6*D_;

  const int r8 = lane >> 3, sl = lane & 7;
  const int c_l = tid & 63, ob = tid >> 6;
  const int gcol = c0 + c_l;
  const bool cok = (gcol < D_);

  f32x4 acc[4][4];
  #pragma unroll
  for (int a = 0; a < 4; ++a)
    #pragma unroll
    for (int b = 0; b < 4; ++b) acc[a][b] = (f32x4){0.f,0.f,0.f,0.f};

  for (int t = z; t < 33; t += nz) {
    const int kt = t * 64;
    __syncthreads();

    #pragma unroll
    for (int i = 0; i < 8; ++i) {
      int row_l = wid*64 + i*8 + r8;
      int sslot = sl ^ (row_l & 7);
      gload_lds16(A + (size_t)(m0 + row_l)*lda + kt + sslot*8, &As[(wid*64 + i*8)*64]);
    }

    #pragma unroll
    for (int it = 0; it < 2; ++it) {
      int o  = ob + it*4;
      int kb = kt + o*8;
      unsigned short u[8];
      #pragma unroll
      for (int j = 0; j < 8; ++j) {
        int k = kb + j;
        float v = 0.f;
        if (cok && k < KTOT)
          v = (k < ksplit) ? B0[(size_t)k*D_ + gcol]
                           : B1[(size_t)(k - ksplit)*D_ + gcol];
        u[j] = f2bf(v);
      }
      *reinterpret_cast<short8*>(&Bs[c_l*80 + ((o ^ (c_l & 7)) << 3)]) =
          *reinterpret_cast<const short8*>(u);
    }

    __syncthreads();

    #pragma unroll
    for (int kk = 0; kk < 2; ++kk) {
      const int q = kk*4 + lg;
      short8 bfr[4];
      #pragma unroll
      for (int b = 0; b < 4; ++b) {
        int col = b*16 + lr;
        bfr[b] = *reinterpret_cast<const short8*>(&Bs[col*80 + ((q ^ (col & 7)) << 3)]);
      }
      #pragma unroll
      for (int a = 0; a < 4; ++a) {
        int row = wid*64 + a*16 + lr;
        short8 af = *reinterpret_cast<const short8*>(&As[row*64 + ((q ^ (row & 7)) << 3)]);
        #pragma unroll
        for (int b = 0; b < 4; ++b)
          acc[a][b] = __builtin_amdgcn_mfma_f32_16x16x32_bf16(af, bfr[b], acc[a][b], 0, 0, 0);
      }
    }
  }

  float* o = P1 + (size_t)z * (size_t)B_ * PLD;
  #pragma unroll
  for (int a = 0; a < 4; ++a) {
    int row = m0 + wid*64 + a*16 + lg*4;
    #pragma unroll
    for (int b = 0; b < 4; ++b) {
      int col = c0 + b*16 + lr;
      if (col < D_) {
        #pragma unroll
        for (int i = 0; i < 4; ++i)
          o[(size_t)(row + i)*PLD + col] = acc[a][b][i];
      }
    }
  }
}

// ---------------- K1c: reduce z-partials, leaky, emit bf16 X0H [512][320] ----------------
__global__ __launch_bounds__(256) void k1c_reduce(
    const float* __restrict__ part, int nz, unsigned short* __restrict__ X0Hbf)
{
  int idx = blockIdx.x*256 + threadIdx.x;
  if (idx >= B_*XLD) return;
  int m = idx / XLD, c = idx % XLD;
  float v = 0.f;
  if (c < D_) {
    for (int zz = 0; zz < nz; ++zz) v += part[(size_t)zz*B_*PLD + (size_t)m*PLD + c];
    v = (v >= 0.f) ? v : 0.1f*v;
  }
  X0Hbf[idx] = f2bf(v);
}

// ---------------- wtrans2: W[300][C] fp32 -> Wtt octet-major bf16 ----------------
// Wtt unit (16B) index = k_oct * Cpad + col; holds W[k_oct*8 .. +7][col] as 8 bf16.
__global__ __launch_bounds__(256) void wtrans2(
    const float* __restrict__ W, int C, int Cpad, unsigned short* __restrict__ Wtt)
{
  __shared__ float lds[64][65];
  const int tid = threadIdx.x;
  const int c0 = blockIdx.x * 64;
  const int k0 = blockIdx.y * 64;
  const int col = tid & 63;
  const int w = tid >> 6;

  // read 64k x 64c tile, coalesced rows
  #pragma unroll
  for (int p = 0; p < 16; ++p) {
    int kl = w*16 + p;
    int k = k0 + kl;
    float v = 0.f;
    if (k < D_ && c0 + col < C) v = W[(size_t)k*C + c0 + col];
    lds[kl][col] = v;
  }
  __syncthreads();

  // write octet-major: wave w handles octets w*2, w*2+1
  #pragma unroll
  for (int q2 = 0; q2 < 2; ++q2) {
    int octl = w*2 + q2;
    unsigned short u[8];
    #pragma unroll
    for (int j = 0; j < 8; ++j) u[j] = f2bf(lds[octl*8 + j][col]);
    size_t goct = (size_t)(k0 >> 3) + octl;
    *reinterpret_cast<short8*>(&Wtt[(goct*Cpad + c0 + col) * 8]) =
        *reinterpret_cast<const short8*>(u);
  }
}

// ---------------- gemm7: heads. A-in-registers, B via DMA, 3-buf rotation ----------------
// 256 thr = 4 waves; block = 128 rows x 64 cols per tile; wave owns 32 rows (2 a-frags),
// full K=320 in 80 VGPRs. Per 64-k stage: 8 DMA (2/wave) + 16 MFMA/wave.
__global__ __launch_bounds__(256, 3) void gemm7(
    const unsigned short* __restrict__ X0H,
    const unsigned short* __restrict__ Wttg, const unsigned short* __restrict__ Wtts,
    const float* __restrict__ bg, const float* __restrict__ bs,
    float* __restrict__ out, float2* __restrict__ Pg, float2* __restrict__ Ps)
{
  __shared__ unsigned short Bs[3][8*64*8];   // 3 bufs x 8KB

  // XCD-chunked bijective swizzle (grid 1176 = 8*147)
  int bid = blockIdx.x;
  int id = (bid & 7) * 147 + (bid >> 3);
  const int mb = id & 3, g = id >> 2;
  const int m0 = mb * 128;

  const int tid = threadIdx.x;
  const int lane = tid & 63, w = tid >> 6;
  const int lr = lane & 15, lg = lane >> 4;

  // ---- A fragments in registers (once) ----
  short8 af0[10], af1[10];
  {
    const unsigned short* A0 = X0H + (size_t)(m0 + w*32 + 0  + lr) * XLD + lg*8;
    const unsigned short* A1 = X0H + (size_t)(m0 + w*32 + 16 + lr) * XLD + lg*8;
    #pragma unroll
    for (int ks = 0; ks < 10; ++ks) {
      af0[ks] = *reinterpret_cast<const short8*>(A0 + ks*32);
      af1[ks] = *reinterpret_cast<const short8*>(A1 + ks*32);
    }
  }

  const int ntile = (1172 - g) / GRP + 1;   // g in 0..293
  const int nsu = ntile * 5;

  f32x4 acc[2][4];

  auto issue_dma = [&](int su, int buf) {
    int t = g + (su / 5) * GRP;
    int j = su % 5;
    const unsigned short* Wtt = (t < NCBG) ? Wttg : Wtts;
    int cp = (t < NCBG) ? CPADG : CPADS;
    int cb = (t < NCBG) ? t : t - NCBG;
    const unsigned short* src = Wtt + ((size_t)(j*8) * cp + cb*64 + lane) * 8;
    #pragma unroll
    for (int i2 = 0; i2 < 2; ++i2) {
      int o = w*2 + i2;
      gload_lds16(src + (size_t)o * cp * 8, &Bs[buf][o * 512]);
    }
  };

  issue_dma(0, 0);
  if (nsu > 1) issue_dma(1, 1);

  for (int su = 0; su < nsu; ++su) {
    const int j = su % 5;
    if (j == 0) {
      #pragma unroll
      for (int a = 0; a < 2; ++a)
        #pragma unroll
        for (int b = 0; b < 4; ++b) acc[a][b] = (f32x4){0.f,0.f,0.f,0.f};
    }
    __syncthreads();                       // vmcnt(0) drain: buf[su%3] ready; buf[(su+2)%3] free
    if (su + 2 < nsu) issue_dma(su + 2, (su + 2) % 3);

    const unsigned short* bb = Bs[su % 3];
    #pragma unroll
    for (int kk = 0; kk < 2; ++kk) {
      const int ks = j*2 + kk;
      short8 bfr[4];
      #pragma unroll
      for (int b = 0; b < 4; ++b)
        bfr[b] = *reinterpret_cast<const short8*>(&bb[(kk*4 + lg)*512 + (b*16 + lr)*8]);
      #pragma unroll
      for (int b = 0; b < 4; ++b) {
        acc[0][b] = __builtin_amdgcn_mfma_f32_16x16x32_bf16(af0[ks], bfr[b], acc[0][b], 0, 0, 0);
        acc[1][b] = __builtin_amdgcn_mfma_f32_16x16x32_bf16(af1[ks], bfr[b], acc[1][b], 0, 0, 0);
      }
    }

    if (j == 4) {
      // ---- epilogue for tile t ----
      int t = g + (su / 5) * GRP;
      bool hg = (t < NCBG);
      const float* bia = hg ? bg : bs;
      int C = hg ? NG_ : NS_;
      float* outp = hg ? out : out + (size_t)B_*NG_;
      float2* part = hg ? Pg : Ps;
      int ldp = hg ? NCBG : NCBS;
      int cb = hg ? t : t - NCBG;
      int c0 = cb * 64;

      float bv[4]; bool okc[4];
      #pragma unroll
      for (int b = 0; b < 4; ++b) {
        int col = c0 + b*16 + lr;
        okc[b] = (col < C);
        bv[b] = okc[b] ? bia[col] : 0.f;
      }
      #pragma unroll
      for (int a = 0; a < 2; ++a) {
        #pragma unroll
        for (int i = 0; i < 4; ++i) {
          int row = m0 + w*32 + a*16 + lg*4 + i;
          float v[4], mx = -3.0e38f;
          #pragma unroll
          for (int b = 0; b < 4; ++b) {
            v[b] = okc[b] ? (acc[a][b][i] + bv[b]) : -3.0e38f;
            mx = fmaxf(mx, v[b]);
          }
          #pragma unroll
          for (int b = 0; b < 4; ++b)
            if (okc[b]) outp[(size_t)row*C + c0 + b*16 + lr] = v[b];
          #pragma unroll
          for (int off = 1; off < 16; off <<= 1) mx = fmaxf(mx, __shfl_xor(mx, off));
          float s = 0.f;
          #pragma unroll
          for (int b = 0; b < 4; ++b) s += __expf(v[b] - mx);
          #pragma unroll
          for (int off = 1; off < 16; off <<= 1) s += __shfl_xor(s, off);
          if (lr == 0) part[(size_t)row*ldp + cb] = make_float2(mx, s);
        }
      }
    }
  }
}

// ---------------- K5: combine (m,s) partials -> lse[1024] ----------------
__global__ __launch_bounds__(256) void k5_lse(
    const float2* __restrict__ pg, const float2* __restrict__ ps,
    float* __restrict__ lse)
{
  int row = blockIdx.x;
  const float2* p; int n;
  if (row < B_) { p = pg + (size_t)row*NCBG; n = NCBG; }
  else          { p = ps + (size_t)(row - B_)*NCBS; n = NCBS; }
  float m = -3.0e38f, s = 0.f;
  for (int i = threadIdx.x; i < n; i += 256) {
    float2 v = p[i];
    float mn = fmaxf(m, v.x);
    s = s*__expf(m - mn) + v.y*__expf(v.x - mn);
    m = mn;
  }
  #pragma unroll
  for (int off = 1; off < 64; off <<= 1) {
    float m2 = __shfl_xor(m, off), s2 = __shfl_xor(s, off);
    float mn = fmaxf(m, m2);
    s = s*__expf(m - mn) + s2*__expf(m2 - mn);
    m = mn;
  }
  __shared__ float ms[4], ss2[4];
  int w = threadIdx.x >> 6;
  if ((threadIdx.x & 63) == 0) { ms[w] = m; ss2[w] = s; }
  __syncthreads();
  if (threadIdx.x == 0) {
    float M = ms[0], S = ss2[0];
    #pragma unroll
    for (int ww = 1; ww < 4; ++ww) {
      float mn = fmaxf(M, ms[ww]);
      S = S*__expf(M - mn) + ss2[ww]*__expf(ms[ww] - mn);
      M = mn;
    }
    lse[row] = M + __logf(S);
  }
}

// ---------------- K4: out -= lse[row], float4 ----------------
__global__ void k4_sub(float* __restrict__ out, const float* __restrict__ lse)
{
  const size_t g4 = (size_t)B_*NG_/4;
  const size_t total4 = g4 + (size_t)B_*NS_/4;
  size_t stride = (size_t)gridDim.x * blockDim.x;
  for (size_t i4 = (size_t)blockIdx.x*blockDim.x + threadIdx.x; i4 < total4; i4 += stride) {
    int row;
    if (i4 < g4) row = (int)(i4 / (NG_/4));
    else         row = B_ + (int)((i4 - g4) / (NS_/4));
    float l = lse[row];
    float4 v = reinterpret_cast<float4*>(out)[i4];
    v.x -= l; v.y -= l; v.z -= l; v.w -= l;
    reinterpret_cast<float4*>(out)[i4] = v;
  }
}

// =====================================================================
extern "C" void kernel_launch(void* const* d_in, const int* in_sizes, int n_in,
                              void* d_out, int out_size, void* d_ws, size_t ws_size,
                              hipStream_t stream)
{
  const float* x    = (const float*)d_in[0];
  const int*   ei   = (const int*)  d_in[1];
  const int*   et   = (const int*)  d_in[2];
  const float* Wrel = (const float*)d_in[3];
  const float* W0   = (const float*)d_in[4];
  const float* Wg   = (const float*)d_in[5];
  const float* bg   = (const float*)d_in[6];
  const float* Ws   = (const float*)d_in[7];
  const float* bs   = (const float*)d_in[8];
  float* out = (float*)d_out;

  // ws layout (bytes): Ybf | X0H | P1 | Pg | Ps | LSE | Wttg | Wtts (~60.3 MB)
  char* p = (char*)d_ws;
  unsigned short* Ybf = (unsigned short*)p;  p += (size_t)B_*YLD*2;
  unsigned short* X0H = (unsigned short*)p;  p += (size_t)B_*XLD*2;
  float*  P1  = (float*)p;                   p += (size_t)8*B_*PLD*4;
  float2* Pg  = (float2*)p;                  p += (size_t)B_*NCBG*8;
  float2* Ps  = (float2*)p;                  p += (size_t)B_*NCBS*8;
  float*  LSE = (float*)p;                   p += 4096;
  unsigned short* Wttg = (unsigned short*)p; p += (size_t)40*CPADG*16;
  unsigned short* Wtts = (unsigned short*)p;

  // W pre-transpose (octet-major bf16)
  wtrans2<<<dim3(CPADG/64, 5), 256, 0, stream>>>(Wg, NG_, CPADG, Wttg);
  wtrans2<<<dim3(CPADS/64, 5), 256, 0, stream>>>(Ws, NS_, CPADS, Wtts);

  k1a_coef_y<<<B_, 256, 0, stream>>>(x, ei, et, Ybf);

  // k1b: P1[z] = Y @ [Wrel;W0] partials (z-split over 33 K-tiles)
  gemm_k1b<<<2*5*8, 256, 0, stream>>>(Ybf, YLD, Wrel, W0, P1, 8);
  k1c_reduce<<<(B_*XLD + 255)/256, 256, 0, stream>>>(P1, 8, X0H);

  // heads: logits (+bias) -> out, per-block (max,sumexp) -> Pg/Ps
  gemm7<<<4*GRP, 256, 0, stream>>>(X0H, Wttg, Wtts, bg, bs, out, Pg, Ps);

  k5_lse<<<2*B_, 256, 0, stream>>>(Pg, Ps, LSE);
  k4_sub<<<2048, 256, 0, stream>>>(out, LSE);
}

// Round 9
// 253.878 us; speedup vs baseline: 1.5795x; 1.2775x over previous
//
#include <hip/hip_runtime.h>
#include <hip/hip_bf16.h>
#include <math.h>

#define B_ 512
#define N_ 32
#define D_ 300
#define R_ 6
#define E_ 256
#define NG_ 50000
#define NS_ 25000

#define KTOT 2100      // 6*300 (Wrel) + 300 (W0)
#define YLD  2112      // Y bf16 leading dim (33*64)
#define XLD  320       // X0H bf16 leading dim (5*64)
#define PLD  304       // k1b partial leading dim (fp32)
#define NCBG 782       // ceil(50000/64)
#define NCBS 391       // ceil(25000/64)
#define CPADG (NCBG*64)   // 50048
#define CPADS (NCBS*64)   // 25024
#define NTILE (NCBG+NCBS) // 1173

typedef __attribute__((ext_vector_type(8))) short short8;
typedef __attribute__((ext_vector_type(4))) float f32x4;

__device__ __forceinline__ unsigned short f2bf(float f) {
  __hip_bfloat16 h = __float2bfloat16(f);
  return *reinterpret_cast<unsigned short*>(&h);
}

__device__ __forceinline__ void gload_lds16(const unsigned short* g, unsigned short* l) {
  __builtin_amdgcn_global_load_lds(
      (const __attribute__((address_space(1))) void*)g,
      (__attribute__((address_space(3))) void*)l,
      16, 0, 0);
}

// ---------------- K1a: collapse graph to Y[b, 2112] bf16 (zero k-pad) ----------------
__global__ __launch_bounds__(256) void k1a_coef_y(
    const float* __restrict__ x, const int* __restrict__ ei,
    const int* __restrict__ et, unsigned short* __restrict__ Y)
{
  int b = blockIdx.x;
  int tid = threadIdx.x;
  __shared__ int srcs[E_], dsts[E_], ets[E_];
  __shared__ int degc[R_*N_];
  __shared__ float coef[R_*N_];

  srcs[tid] = ei[b*2*E_ + tid];
  dsts[tid] = ei[b*2*E_ + E_ + tid];
  ets[tid]  = et[b*E_ + tid];
  if (tid < R_*N_) { degc[tid] = 0; coef[tid] = 0.0f; }
  __syncthreads();

  atomicAdd(&degc[ets[tid]*N_ + dsts[tid]], 1);
  __syncthreads();

  if (dsts[tid] == 0) {
    int r = ets[tid];
    float ds = 1.0f + (float)degc[r*N_ + srcs[tid]];
    float dd = 1.0f + (float)degc[r*N_ + 0];
    atomicAdd(&coef[r*N_ + srcs[tid]], rsqrtf(ds*dd));
  }
  if (tid < R_) {
    atomicAdd(&coef[tid*N_ + 0], 1.0f/(1.0f + (float)degc[tid*N_]));
  }
  __syncthreads();

  const float* xb = x + (size_t)b*N_*D_;
  unsigned short* Yb = Y + (size_t)b*YLD;
  for (int k = tid; k < D_; k += 256) {
    #pragma unroll
    for (int r = 0; r < R_; ++r) {
      float acc = 0.0f;
      for (int n = 0; n < N_; ++n) {
        float c = coef[r*N_ + n];          // uniform across threads
        if (c != 0.0f) acc += c * xb[n*D_ + k];
      }
      Yb[r*D_ + k] = f2bf(acc);
    }
    Yb[6*D_ + k] = f2bf(xb[k]);            // x[b,0,:] for the W0 term
  }
  if (tid < YLD - KTOT) Yb[KTOT + tid] = 0;
}

// ---------------- k1b gemm (round-5 proven): BM=256, BN=64, BK=64 ----------------
__global__ __launch_bounds__(256, 3) void gemm_k1b(
    const unsigned short* __restrict__ A, int lda,
    const float* __restrict__ B0, const float* __restrict__ B1,
    float* __restrict__ P1, int nz)
{
  __shared__ unsigned short As[256*64];
  __shared__ unsigned short Bs[64*80];

  const int tid  = threadIdx.x;
  const int lane = tid & 63, wid = tid >> 6;
  const int lr = lane & 15, lg = lane >> 4;

  int id = blockIdx.x;          // 2 mb * 5 cb * nz
  int mb = id & 1; id >>= 1;
  int cb = id % 5, z = id / 5;
  const int m0 = mb*256, c0 = cb*64;
  const int ksplit = 6*D_;

  const int r8 = lane >> 3, sl = lane & 7;
  const int c_l = tid & 63, ob = tid >> 6;
  const int gcol = c0 + c_l;
  const bool cok = (gcol < D_);

  f32x4 acc[4][4];
  #pragma unroll
  for (int a = 0; a < 4; ++a)
    #pragma unroll
    for (int b = 0; b < 4; ++b) acc[a][b] = (f32x4){0.f,0.f,0.f,0.f};

  for (int t = z; t < 33; t += nz) {
    const int kt = t * 64;
    __syncthreads();

    #pragma unroll
    for (int i = 0; i < 8; ++i) {
      int row_l = wid*64 + i*8 + r8;
      int sslot = sl ^ (row_l & 7);
      gload_lds16(A + (size_t)(m0 + row_l)*lda + kt + sslot*8, &As[(wid*64 + i*8)*64]);
    }

    #pragma unroll
    for (int it = 0; it < 2; ++it) {
      int o  = ob + it*4;
      int kb = kt + o*8;
      unsigned short u[8];
      #pragma unroll
      for (int j = 0; j < 8; ++j) {
        int k = kb + j;
        float v = 0.f;
        if (cok && k < KTOT)
          v = (k < ksplit) ? B0[(size_t)k*D_ + gcol]
                           : B1[(size_t)(k - ksplit)*D_ + gcol];
        u[j] = f2bf(v);
      }
      *reinterpret_cast<short8*>(&Bs[c_l*80 + ((o ^ (c_l & 7)) << 3)]) =
          *reinterpret_cast<const short8*>(u);
    }

    __syncthreads();

    #pragma unroll
    for (int kk = 0; kk < 2; ++kk) {
      const int q = kk*4 + lg;
      short8 bfr[4];
      #pragma unroll
      for (int b = 0; b < 4; ++b) {
        int col = b*16 + lr;
        bfr[b] = *reinterpret_cast<const short8*>(&Bs[col*80 + ((q ^ (col & 7)) << 3)]);
      }
      #pragma unroll
      for (int a = 0; a < 4; ++a) {
        int row = wid*64 + a*16 + lr;
        short8 af = *reinterpret_cast<const short8*>(&As[row*64 + ((q ^ (row & 7)) << 3)]);
        #pragma unroll
        for (int b = 0; b < 4; ++b)
          acc[a][b] = __builtin_amdgcn_mfma_f32_16x16x32_bf16(af, bfr[b], acc[a][b], 0, 0, 0);
      }
    }
  }

  float* o = P1 + (size_t)z * (size_t)B_ * PLD;
  #pragma unroll
  for (int a = 0; a < 4; ++a) {
    int row = m0 + wid*64 + a*16 + lg*4;
    #pragma unroll
    for (int b = 0; b < 4; ++b) {
      int col = c0 + b*16 + lr;
      if (col < D_) {
        #pragma unroll
        for (int i = 0; i < 4; ++i)
          o[(size_t)(row + i)*PLD + col] = acc[a][b][i];
      }
    }
  }
}

// ---------------- K1c: reduce z-partials, leaky, emit bf16 X0H [512][320] ----------------
__global__ __launch_bounds__(256) void k1c_reduce(
    const float* __restrict__ part, int nz, unsigned short* __restrict__ X0Hbf)
{
  int idx = blockIdx.x*256 + threadIdx.x;
  if (idx >= B_*XLD) return;
  int m = idx / XLD, c = idx % XLD;
  float v = 0.f;
  if (c < D_) {
    for (int zz = 0; zz < nz; ++zz) v += part[(size_t)zz*B_*PLD + (size_t)m*PLD + c];
    v = (v >= 0.f) ? v : 0.1f*v;
  }
  X0Hbf[idx] = f2bf(v);
}

// ---------------- wtrans2: W[300][C] fp32 -> Wtt octet-major bf16 ----------------
// Wtt unit (16B) index = k_oct * Cpad + col; holds W[k_oct*8 .. +7][col] as 8 bf16.
__global__ __launch_bounds__(256) void wtrans2(
    const float* __restrict__ W, int C, int Cpad, unsigned short* __restrict__ Wtt)
{
  __shared__ float lds[64][65];
  const int tid = threadIdx.x;
  const int c0 = blockIdx.x * 64;
  const int k0 = blockIdx.y * 64;
  const int col = tid & 63;
  const int w = tid >> 6;

  #pragma unroll
  for (int p = 0; p < 16; ++p) {
    int kl = w*16 + p;
    int k = k0 + kl;
    float v = 0.f;
    if (k < D_ && c0 + col < C) v = W[(size_t)k*C + c0 + col];
    lds[kl][col] = v;
  }
  __syncthreads();

  #pragma unroll
  for (int q2 = 0; q2 < 2; ++q2) {
    int octl = w*2 + q2;
    unsigned short u[8];
    #pragma unroll
    for (int j = 0; j < 8; ++j) u[j] = f2bf(lds[octl*8 + j][col]);
    size_t goct = (size_t)(k0 >> 3) + octl;
    *reinterpret_cast<short8*>(&Wtt[(goct*Cpad + c0 + col) * 8]) =
        *reinterpret_cast<const short8*>(u);
  }
}

// ---------------- gemm8: heads. BM=512 (W read ONCE), A fully in regs ----------------
// 512 thr = 8 waves; wave owns 64 rows x K=320 (af[4][10], 160 VGPR).
// Grid 256 (1 block/CU); block grid-strides col-tiles bid, bid+256, ...
// B: one DMA per wave per 64k-stage into 3-buf LDS; counted vmcnt(1) + raw barrier.
__global__ __launch_bounds__(512, 2) void gemm8(
    const unsigned short* __restrict__ X0H,
    const unsigned short* __restrict__ Wttg, const unsigned short* __restrict__ Wtts,
    const float* __restrict__ bg, const float* __restrict__ bs,
    float* __restrict__ out, float2* __restrict__ Pg, float2* __restrict__ Ps)
{
  __shared__ unsigned short BsF[3*4096];   // 3 bufs x 8KB

  const int bid = blockIdx.x;
  const int tid = threadIdx.x;
  const int lane = tid & 63, w = tid >> 6;
  const int lr = lane & 15, lg = lane >> 4;

  const int nt  = 1 + (NTILE - 1 - bid) / 256;   // 4 or 5 tiles
  const int nsu = nt * 5;

  auto dma = [&](int su2) {
    int tl2 = su2 / 5, j2 = su2 % 5;
    int tt2 = bid + tl2*256;
    const unsigned short* wt; size_t cp; int cb2;
    if (tt2 < NCBG) { wt = Wttg; cp = CPADG; cb2 = tt2; }
    else            { wt = Wtts; cp = CPADS; cb2 = tt2 - NCBG; }
    const unsigned short* g = wt + ((size_t)(j2*8 + w)*cp + (size_t)cb2*64 + lane)*8;
    gload_lds16(g, &BsF[(su2 % 3)*4096 + w*512]);
  };

  // prologue: 2 stages of DMA in flight, then A into registers (once)
  dma(0);
  dma(1);

  short8 af[4][10];
  #pragma unroll
  for (int a = 0; a < 4; ++a) {
    const unsigned short* Ar = X0H + (size_t)(w*64 + a*16 + lr)*XLD + lg*8;
    #pragma unroll
    for (int ks = 0; ks < 10; ++ks)
      af[a][ks] = *reinterpret_cast<const short8*>(Ar + ks*32);
  }

  f32x4 acc[4][4];

#define STAGE8(j) do {                                                         \
    asm volatile("s_waitcnt vmcnt(1)" ::: "memory");                           \
    __builtin_amdgcn_s_barrier();                                              \
    __builtin_amdgcn_sched_barrier(0);                                         \
    { int gsu = tl*5 + (j); if (gsu + 2 < nsu) dma(gsu + 2); }                 \
    {                                                                          \
      const unsigned short* bb = &BsF[((tl*5 + (j)) % 3)*4096];                \
      _Pragma("unroll")                                                        \
      for (int kk = 0; kk < 2; ++kk) {                                         \
        short8 bfr[4];                                                         \
        _Pragma("unroll")                                                      \
        for (int b = 0; b < 4; ++b)                                            \
          bfr[b] = *reinterpret_cast<const short8*>(                           \
              &bb[(kk*4 + lg)*512 + (b*16 + lr)*8]);                           \
        _Pragma("unroll")                                                      \
        for (int a = 0; a < 4; ++a)                                            \
          _Pragma("unroll")                                                    \
          for (int b = 0; b < 4; ++b)                                          \
            acc[a][b] = __builtin_amdgcn_mfma_f32_16x16x32_bf16(               \
                af[a][(j)*2 + kk], bfr[b], acc[a][b], 0, 0, 0);                \
      }                                                                        \
    }                                                                          \
  } while (0)

  for (int tl = 0; tl < nt; ++tl) {
    const int tt = bid + tl*256;

    #pragma unroll
    for (int a = 0; a < 4; ++a)
      #pragma unroll
      for (int b = 0; b < 4; ++b) acc[a][b] = (f32x4){0.f,0.f,0.f,0.f};

    STAGE8(0);
    STAGE8(1);
    STAGE8(2);
    STAGE8(3);
    STAGE8(4);

    // ---- epilogue for tile tt ----
    const bool hg = (tt < NCBG);
    const float* bia = hg ? bg : bs;
    const int C = hg ? NG_ : NS_;
    float* outp = hg ? out : out + (size_t)B_*NG_;
    float2* part = hg ? Pg : Ps;
    const int cb = hg ? tt : tt - NCBG;
    const int c0 = cb * 64;

    float bv[4]; bool okc[4];
    #pragma unroll
    for (int b = 0; b < 4; ++b) {
      int col = c0 + b*16 + lr;
      okc[b] = (col < C);
      bv[b] = okc[b] ? bia[col] : 0.f;
    }
    #pragma unroll
    for (int a = 0; a < 4; ++a) {
      #pragma unroll
      for (int i = 0; i < 4; ++i) {
        int row = w*64 + a*16 + lg*4 + i;
        float v[4], mx = -3.0e38f;
        #pragma unroll
        for (int b = 0; b < 4; ++b) {
          v[b] = okc[b] ? (acc[a][b][i] + bv[b]) : -3.0e38f;
          mx = fmaxf(mx, v[b]);
        }
        #pragma unroll
        for (int b = 0; b < 4; ++b)
          if (okc[b]) outp[(size_t)row*C + c0 + b*16 + lr] = v[b];
        #pragma unroll
        for (int off = 1; off < 16; off <<= 1) mx = fmaxf(mx, __shfl_xor(mx, off));
        float s = 0.f;
        #pragma unroll
        for (int b = 0; b < 4; ++b) s += __expf(v[b] - mx);
        #pragma unroll
        for (int off = 1; off < 16; off <<= 1) s += __shfl_xor(s, off);
        if (lr == 0) part[(size_t)cb*512 + row] = make_float2(mx, s);
      }
    }
  }
#undef STAGE8
}

// ---------------- k5b: combine tile-major (m,s) partials -> lse[1024] ----------------
// part layout: [tile][row(512)] float2. Block handles 8 rows; 256 thr = 8 rows x 32 t-slots.
__global__ __launch_bounds__(256) void k5b(
    const float2* __restrict__ Pg, const float2* __restrict__ Ps,
    float* __restrict__ lse)
{
  const int blk = blockIdx.x;            // 0..127
  const bool hg = (blk < 64);
  const float2* p = hg ? Pg : Ps;
  const int n = hg ? NCBG : NCBS;
  const int r0 = (hg ? blk : blk - 64) * 8;
  const int tid = threadIdx.x;
  const int rr = tid & 7;
  const int row = r0 + rr;

  float m = -3.0e38f, s = 0.f;
  for (int t = tid >> 3; t < n; t += 32) {
    float2 v = p[(size_t)t*512 + row];
    float mn = fmaxf(m, v.x);
    s = s*__expf(m - mn) + v.y*__expf(v.x - mn);
    m = mn;
  }
  // reduce across t-slots (same row): lanes differ in bits 3..5 within a wave
  #pragma unroll
  for (int off = 8; off < 64; off <<= 1) {
    float m2 = __shfl_xor(m, off), s2 = __shfl_xor(s, off);
    float mn = fmaxf(m, m2);
    s = s*__expf(m - mn) + s2*__expf(m2 - mn);
    m = mn;
  }
  __shared__ float ms[4][8], ss[4][8];
  const int wv = tid >> 6;
  if ((tid & 63) < 8) { ms[wv][tid & 7] = m; ss[wv][tid & 7] = s; }
  __syncthreads();
  if (tid < 8) {
    float M = ms[0][tid], S = ss[0][tid];
    #pragma unroll
    for (int ww = 1; ww < 4; ++ww) {
      float mn = fmaxf(M, ms[ww][tid]);
      S = S*__expf(M - mn) + ss[ww][tid]*__expf(ms[ww][tid] - mn);
      M = mn;
    }
    lse[(hg ? 0 : 512) + r0 + tid] = M + __logf(S);
  }
}

// ---------------- K4: out -= lse[row], float4 ----------------
__global__ void k4_sub(float* __restrict__ out, const float* __restrict__ lse)
{
  const size_t g4 = (size_t)B_*NG_/4;
  const size_t total4 = g4 + (size_t)B_*NS_/4;
  size_t stride = (size_t)gridDim.x * blockDim.x;
  for (size_t i4 = (size_t)blockIdx.x*blockDim.x + threadIdx.x; i4 < total4; i4 += stride) {
    int row;
    if (i4 < g4) row = (int)(i4 / (NG_/4));
    else         row = B_ + (int)((i4 - g4) / (NS_/4));
    float l = lse[row];
    float4 v = reinterpret_cast<float4*>(out)[i4];
    v.x -= l; v.y -= l; v.z -= l; v.w -= l;
    reinterpret_cast<float4*>(out)[i4] = v;
  }
}

// =====================================================================
extern "C" void kernel_launch(void* const* d_in, const int* in_sizes, int n_in,
                              void* d_out, int out_size, void* d_ws, size_t ws_size,
                              hipStream_t stream)
{
  const float* x    = (const float*)d_in[0];
  const int*   ei   = (const int*)  d_in[1];
  const int*   et   = (const int*)  d_in[2];
  const float* Wrel = (const float*)d_in[3];
  const float* W0   = (const float*)d_in[4];
  const float* Wg   = (const float*)d_in[5];
  const float* bg   = (const float*)d_in[6];
  const float* Ws   = (const float*)d_in[7];
  const float* bs   = (const float*)d_in[8];
  float* out = (float*)d_out;

  // ws layout (bytes): Ybf | X0H | P1 | Pg | Ps | LSE | Wttg | Wtts (~60.3 MB)
  char* p = (char*)d_ws;
  unsigned short* Ybf = (unsigned short*)p;  p += (size_t)B_*YLD*2;
  unsigned short* X0H = (unsigned short*)p;  p += (size_t)B_*XLD*2;
  float*  P1  = (float*)p;                   p += (size_t)8*B_*PLD*4;
  float2* Pg  = (float2*)p;                  p += (size_t)NCBG*512*8;
  float2* Ps  = (float2*)p;                  p += (size_t)NCBS*512*8;
  float*  LSE = (float*)p;                   p += 4096;
  unsigned short* Wttg = (unsigned short*)p; p += (size_t)40*CPADG*16;
  unsigned short* Wtts = (unsigned short*)p;

  // W pre-transpose (octet-major bf16)
  wtrans2<<<dim3(CPADG/64, 5), 256, 0, stream>>>(Wg, NG_, CPADG, Wttg);
  wtrans2<<<dim3(CPADS/64, 5), 256, 0, stream>>>(Ws, NS_, CPADS, Wtts);

  k1a_coef_y<<<B_, 256, 0, stream>>>(x, ei, et, Ybf);

  // k1b: P1[z] = Y @ [Wrel;W0] partials (z-split over 33 K-tiles)
  gemm_k1b<<<2*5*8, 256, 0, stream>>>(Ybf, YLD, Wrel, W0, P1, 8);
  k1c_reduce<<<(B_*XLD + 255)/256, 256, 0, stream>>>(P1, 8, X0H);

  // heads: logits (+bias) -> out, per-tile (max,sumexp) -> Pg/Ps
  gemm8<<<256, 512, 0, stream>>>(X0H, Wttg, Wtts, bg, bs, out, Pg, Ps);

  k5b<<<128, 256, 0, stream>>>(Pg, Ps, LSE);
  k4_sub<<<2048, 256, 0, stream>>>(out, LSE);
}

// Round 10
// 248.457 us; speedup vs baseline: 1.6140x; 1.0218x over previous
//
#include <hip/hip_runtime.h>
#include <hip/hip_bf16.h>
#include <math.h>

#define B_ 512
#define N_ 32
#define D_ 300
#define R_ 6
#define E_ 256
#define NG_ 50000
#define NS_ 25000

#define KTOT 2100      // 6*300 (Wrel) + 300 (W0)
#define YLD  2112      // Y bf16 leading dim (33*64)
#define XLD  320       // X0H bf16 leading dim (5*64)
#define PLD  304       // k1b partial leading dim (fp32)
#define NCBG 782       // ceil(50000/64)
#define NCBS 391       // ceil(25000/64)
#define CPADG (NCBG*64)   // 50048
#define CPADS (NCBS*64)   // 25024
#define NTILE (NCBG+NCBS) // 1173

typedef __attribute__((ext_vector_type(8))) short short8;
typedef __attribute__((ext_vector_type(4))) float f32x4;

__device__ __forceinline__ unsigned short f2bf(float f) {
  __hip_bfloat16 h = __float2bfloat16(f);
  return *reinterpret_cast<unsigned short*>(&h);
}

__device__ __forceinline__ void gload_lds16(const unsigned short* g, unsigned short* l) {
  __builtin_amdgcn_global_load_lds(
      (const __attribute__((address_space(1))) void*)g,
      (__attribute__((address_space(3))) void*)l,
      16, 0, 0);
}

// ---------------- K1a: collapse graph to Y[b, 2112] bf16 (zero k-pad) ----------------
__global__ __launch_bounds__(256) void k1a_coef_y(
    const float* __restrict__ x, const int* __restrict__ ei,
    const int* __restrict__ et, unsigned short* __restrict__ Y)
{
  int b = blockIdx.x;
  int tid = threadIdx.x;
  __shared__ int srcs[E_], dsts[E_], ets[E_];
  __shared__ int degc[R_*N_];
  __shared__ float coef[R_*N_];

  srcs[tid] = ei[b*2*E_ + tid];
  dsts[tid] = ei[b*2*E_ + E_ + tid];
  ets[tid]  = et[b*E_ + tid];
  if (tid < R_*N_) { degc[tid] = 0; coef[tid] = 0.0f; }
  __syncthreads();

  atomicAdd(&degc[ets[tid]*N_ + dsts[tid]], 1);
  __syncthreads();

  if (dsts[tid] == 0) {
    int r = ets[tid];
    float ds = 1.0f + (float)degc[r*N_ + srcs[tid]];
    float dd = 1.0f + (float)degc[r*N_ + 0];
    atomicAdd(&coef[r*N_ + srcs[tid]], rsqrtf(ds*dd));
  }
  if (tid < R_) {
    atomicAdd(&coef[tid*N_ + 0], 1.0f/(1.0f + (float)degc[tid*N_]));
  }
  __syncthreads();

  const float* xb = x + (size_t)b*N_*D_;
  unsigned short* Yb = Y + (size_t)b*YLD;
  for (int k = tid; k < D_; k += 256) {
    #pragma unroll
    for (int r = 0; r < R_; ++r) {
      float acc = 0.0f;
      for (int n = 0; n < N_; ++n) {
        float c = coef[r*N_ + n];          // uniform across threads
        if (c != 0.0f) acc += c * xb[n*D_ + k];
      }
      Yb[r*D_ + k] = f2bf(acc);
    }
    Yb[6*D_ + k] = f2bf(xb[k]);            // x[b,0,:] for the W0 term
  }
  if (tid < YLD - KTOT) Yb[KTOT + tid] = 0;
}

// ---------------- k1b gemm (round-5 proven): BM=256, BN=64, BK=64 ----------------
__global__ __launch_bounds__(256, 3) void gemm_k1b(
    const unsigned short* __restrict__ A, int lda,
    const float* __restrict__ B0, const float* __restrict__ B1,
    float* __restrict__ P1, int nz)
{
  __shared__ unsigned short As[256*64];
  __shared__ unsigned short Bs[64*80];

  const int tid  = threadIdx.x;
  const int lane = tid & 63, wid = tid >> 6;
  const int lr = lane & 15, lg = lane >> 4;

  int id = blockIdx.x;          // 2 mb * 5 cb * nz
  int mb = id & 1; id >>= 1;
  int cb = id % 5, z = id / 5;
  const int m0 = mb*256, c0 = cb*64;
  const int ksplit = 6*D_;

  const int r8 = lane >> 3, sl = lane & 7;
  const int c_l = tid & 63, ob = tid >> 6;
  const int gcol = c0 + c_l;
  const bool cok = (gcol < D_);

  f32x4 acc[4][4];
  #pragma unroll
  for (int a = 0; a < 4; ++a)
    #pragma unroll
    for (int b = 0; b < 4; ++b) acc[a][b] = (f32x4){0.f,0.f,0.f,0.f};

  for (int t = z; t < 33; t += nz) {
    const int kt = t * 64;
    __syncthreads();

    #pragma unroll
    for (int i = 0; i < 8; ++i) {
      int row_l = wid*64 + i*8 + r8;
      int sslot = sl ^ (row_l & 7);
      gload_lds16(A + (size_t)(m0 + row_l)*lda + kt + sslot*8, &As[(wid*64 + i*8)*64]);
    }

    #pragma unroll
    for (int it = 0; it < 2; ++it) {
      int o  = ob + it*4;
      int kb = kt + o*8;
      unsigned short u[8];
      #pragma unroll
      for (int j = 0; j < 8; ++j) {
        int k = kb + j;
        float v = 0.f;
        if (cok && k < KTOT)
          v = (k < ksplit) ? B0[(size_t)k*D_ + gcol]
                           : B1[(size_t)(k - ksplit)*D_ + gcol];
        u[j] = f2bf(v);
      }
      *reinterpret_cast<short8*>(&Bs[c_l*80 + ((o ^ (c_l & 7)) << 3)]) =
          *reinterpret_cast<const short8*>(u);
    }

    __syncthreads();

    #pragma unroll
    for (int kk = 0; kk < 2; ++kk) {
      const int q = kk*4 + lg;
      short8 bfr[4];
      #pragma unroll
      for (int b = 0; b < 4; ++b) {
        int col = b*16 + lr;
        bfr[b] = *reinterpret_cast<const short8*>(&Bs[col*80 + ((q ^ (col & 7)) << 3)]);
      }
      #pragma unroll
      for (int a = 0; a < 4; ++a) {
        int row = wid*64 + a*16 + lr;
        short8 af = *reinterpret_cast<const short8*>(&As[row*64 + ((q ^ (row & 7)) << 3)]);
        #pragma unroll
        for (int b = 0; b < 4; ++b)
          acc[a][b] = __builtin_amdgcn_mfma_f32_16x16x32_bf16(af, bfr[b], acc[a][b], 0, 0, 0);
      }
    }
  }

  float* o = P1 + (size_t)z * (size_t)B_ * PLD;
  #pragma unroll
  for (int a = 0; a < 4; ++a) {
    int row = m0 + wid*64 + a*16 + lg*4;
    #pragma unroll
    for (int b = 0; b < 4; ++b) {
      int col = c0 + b*16 + lr;
      if (col < D_) {
        #pragma unroll
        for (int i = 0; i < 4; ++i)
          o[(size_t)(row + i)*PLD + col] = acc[a][b][i];
      }
    }
  }
}

// ---------------- K1c: reduce z-partials, leaky, emit bf16 X0H [512][320] ----------------
__global__ __launch_bounds__(256) void k1c_reduce(
    const float* __restrict__ part, int nz, unsigned short* __restrict__ X0Hbf)
{
  int idx = blockIdx.x*256 + threadIdx.x;
  if (idx >= B_*XLD) return;
  int m = idx / XLD, c = idx % XLD;
  float v = 0.f;
  if (c < D_) {
    for (int zz = 0; zz < nz; ++zz) v += part[(size_t)zz*B_*PLD + (size_t)m*PLD + c];
    v = (v >= 0.f) ? v : 0.1f*v;
  }
  X0Hbf[idx] = f2bf(v);
}

// ---------------- wtrans2: W[300][C] fp32 -> Wtt octet-major bf16 ----------------
// Wtt unit (16B) index = k_oct * Cpad + col; holds W[k_oct*8 .. +7][col] as 8 bf16.
__global__ __launch_bounds__(256) void wtrans2(
    const float* __restrict__ W, int C, int Cpad, unsigned short* __restrict__ Wtt)
{
  __shared__ float lds[64][65];
  const int tid = threadIdx.x;
  const int c0 = blockIdx.x * 64;
  const int k0 = blockIdx.y * 64;
  const int col = tid & 63;
  const int w = tid >> 6;

  #pragma unroll
  for (int p = 0; p < 16; ++p) {
    int kl = w*16 + p;
    int k = k0 + kl;
    float v = 0.f;
    if (k < D_ && c0 + col < C) v = W[(size_t)k*C + c0 + col];
    lds[kl][col] = v;
  }
  __syncthreads();

  #pragma unroll
  for (int q2 = 0; q2 < 2; ++q2) {
    int octl = w*2 + q2;
    unsigned short u[8];
    #pragma unroll
    for (int j = 0; j < 8; ++j) u[j] = f2bf(lds[octl*8 + j][col]);
    size_t goct = (size_t)(k0 >> 3) + octl;
    *reinterpret_cast<short8*>(&Wtt[(goct*Cpad + c0 + col) * 8]) =
        *reinterpret_cast<const short8*>(u);
  }
}

// ---------------- gemm9: heads. BM=512 (W read ONCE), A fully in regs, NO spill ----
// 512 thr = 8 waves; wave owns 64 rows x K=320 (af[4][10], 160 VGPR) -> needs ~244
// VGPR so launch_bounds(512,1) (1 block/CU, 2 waves/SIMD). TLP deficit covered by
// 4-buf LDS + DMA 3 stages ahead + counted vmcnt(2) (in-flight ~3 stages >= HBM lat).
__global__ __launch_bounds__(512, 1) void gemm9(
    const unsigned short* __restrict__ X0H,
    const unsigned short* __restrict__ Wttg, const unsigned short* __restrict__ Wtts,
    const float* __restrict__ bg, const float* __restrict__ bs,
    float* __restrict__ out, float2* __restrict__ Pg, float2* __restrict__ Ps)
{
  __shared__ unsigned short BsF[4*4096];   // 4 bufs x 8KB

  const int bid = blockIdx.x;
  const int tid = threadIdx.x;
  const int lane = tid & 63, w = tid >> 6;
  const int lr = lane & 15, lg = lane >> 4;

  const int nt  = 1 + (NTILE - 1 - bid) / 256;   // 4 or 5 tiles
  const int nsu = nt * 5;

  auto dma = [&](int su2) {
    int tl2 = su2 / 5, j2 = su2 % 5;
    int tt2 = bid + tl2*256;
    const unsigned short* wt; size_t cp; int cb2;
    if (tt2 < NCBG) { wt = Wttg; cp = CPADG; cb2 = tt2; }
    else            { wt = Wtts; cp = CPADS; cb2 = tt2 - NCBG; }
    const unsigned short* g = wt + ((size_t)(j2*8 + w)*cp + (size_t)cb2*64 + lane)*8;
    gload_lds16(g, &BsF[(su2 & 3)*4096 + w*512]);
  };

  // prologue: 3 stages of DMA in flight, then A into registers (once)
  dma(0);
  dma(1);
  dma(2);

  short8 af[4][10];
  #pragma unroll
  for (int a = 0; a < 4; ++a) {
    const unsigned short* Ar = X0H + (size_t)(w*64 + a*16 + lr)*XLD + lg*8;
    #pragma unroll
    for (int ks = 0; ks < 10; ++ks)
      af[a][ks] = *reinterpret_cast<const short8*>(Ar + ks*32);
  }

  f32x4 acc[4][4];

#define STAGE9(j) do {                                                         \
    asm volatile("s_waitcnt vmcnt(2)" ::: "memory");                           \
    __builtin_amdgcn_s_barrier();                                              \
    __builtin_amdgcn_sched_barrier(0);                                         \
    { int gsu = tl*5 + (j); if (gsu + 3 < nsu) dma(gsu + 3); }                 \
    {                                                                          \
      const unsigned short* bb = &BsF[((tl*5 + (j)) & 3)*4096];                \
      _Pragma("unroll")                                                        \
      for (int kk = 0; kk < 2; ++kk) {                                         \
        short8 bfr[4];                                                         \
        _Pragma("unroll")                                                      \
        for (int b = 0; b < 4; ++b)                                            \
          bfr[b] = *reinterpret_cast<const short8*>(                           \
              &bb[(kk*4 + lg)*512 + (b*16 + lr)*8]);                           \
        _Pragma("unroll")                                                      \
        for (int a = 0; a < 4; ++a)                                            \
          _Pragma("unroll")                                                    \
          for (int b = 0; b < 4; ++b)                                          \
            acc[a][b] = __builtin_amdgcn_mfma_f32_16x16x32_bf16(               \
                af[a][(j)*2 + kk], bfr[b], acc[a][b], 0, 0, 0);                \
      }                                                                        \
    }                                                                          \
  } while (0)

  for (int tl = 0; tl < nt; ++tl) {
    const int tt = bid + tl*256;

    #pragma unroll
    for (int a = 0; a < 4; ++a)
      #pragma unroll
      for (int b = 0; b < 4; ++b) acc[a][b] = (f32x4){0.f,0.f,0.f,0.f};

    STAGE9(0);
    STAGE9(1);
    STAGE9(2);
    STAGE9(3);
    STAGE9(4);

    // ---- epilogue for tile tt ----
    const bool hg = (tt < NCBG);
    const float* bia = hg ? bg : bs;
    const int C = hg ? NG_ : NS_;
    float* outp = hg ? out : out + (size_t)B_*NG_;
    float2* part = hg ? Pg : Ps;
    const int cb = hg ? tt : tt - NCBG;
    const int c0 = cb * 64;

    float bv[4]; bool okc[4];
    #pragma unroll
    for (int b = 0; b < 4; ++b) {
      int col = c0 + b*16 + lr;
      okc[b] = (col < C);
      bv[b] = okc[b] ? bia[col] : 0.f;
    }
    #pragma unroll
    for (int a = 0; a < 4; ++a) {
      #pragma unroll
      for (int i = 0; i < 4; ++i) {
        int row = w*64 + a*16 + lg*4 + i;
        float v[4], mx = -3.0e38f;
        #pragma unroll
        for (int b = 0; b < 4; ++b) {
          v[b] = okc[b] ? (acc[a][b][i] + bv[b]) : -3.0e38f;
          mx = fmaxf(mx, v[b]);
        }
        #pragma unroll
        for (int b = 0; b < 4; ++b)
          if (okc[b]) outp[(size_t)row*C + c0 + b*16 + lr] = v[b];
        #pragma unroll
        for (int off = 1; off < 16; off <<= 1) mx = fmaxf(mx, __shfl_xor(mx, off));
        float s = 0.f;
        #pragma unroll
        for (int b = 0; b < 4; ++b) s += __expf(v[b] - mx);
        #pragma unroll
        for (int off = 1; off < 16; off <<= 1) s += __shfl_xor(s, off);
        if (lr == 0) part[(size_t)cb*512 + row] = make_float2(mx, s);
      }
    }
  }
#undef STAGE9
}

// ---------------- k5b: combine tile-major (m,s) partials -> lse[1024] ----------------
// part layout: [tile][row(512)] float2. Block handles 8 rows; 256 thr = 8 rows x 32 t-slots.
__global__ __launch_bounds__(256) void k5b(
    const float2* __restrict__ Pg, const float2* __restrict__ Ps,
    float* __restrict__ lse)
{
  const int blk = blockIdx.x;            // 0..127
  const bool hg = (blk < 64);
  const float2* p = hg ? Pg : Ps;
  const int n = hg ? NCBG : NCBS;
  const int r0 = (hg ? blk : blk - 64) * 8;
  const int tid = threadIdx.x;
  const int rr = tid & 7;
  const int row = r0 + rr;

  float m = -3.0e38f, s = 0.f;
  for (int t = tid >> 3; t < n; t += 32) {
    float2 v = p[(size_t)t*512 + row];
    float mn = fmaxf(m, v.x);
    s = s*__expf(m - mn) + v.y*__expf(v.x - mn);
    m = mn;
  }
  // reduce across t-slots (same row): lanes differ in bits 3..5 within a wave
  #pragma unroll
  for (int off = 8; off < 64; off <<= 1) {
    float m2 = __shfl_xor(m, off), s2 = __shfl_xor(s, off);
    float mn = fmaxf(m, m2);
    s = s*__expf(m - mn) + s2*__expf(m2 - mn);
    m = mn;
  }
  __shared__ float ms[4][8], ss[4][8];
  const int wv = tid >> 6;
  if ((tid & 63) < 8) { ms[wv][tid & 7] = m; ss[wv][tid & 7] = s; }
  __syncthreads();
  if (tid < 8) {
    float M = ms[0][tid], S = ss[0][tid];
    #pragma unroll
    for (int ww = 1; ww < 4; ++ww) {
      float mn = fmaxf(M, ms[ww][tid]);
      S = S*__expf(M - mn) + ss[ww][tid]*__expf(ms[ww][tid] - mn);
      M = mn;
    }
    lse[(hg ? 0 : 512) + r0 + tid] = M + __logf(S);
  }
}

// ---------------- K4: out -= lse[row], float4 ----------------
__global__ void k4_sub(float* __restrict__ out, const float* __restrict__ lse)
{
  const size_t g4 = (size_t)B_*NG_/4;
  const size_t total4 = g4 + (size_t)B_*NS_/4;
  size_t stride = (size_t)gridDim.x * blockDim.x;
  for (size_t i4 = (size_t)blockIdx.x*blockDim.x + threadIdx.x; i4 < total4; i4 += stride) {
    int row;
    if (i4 < g4) row = (int)(i4 / (NG_/4));
    else         row = B_ + (int)((i4 - g4) / (NS_/4));
    float l = lse[row];
    float4 v = reinterpret_cast<float4*>(out)[i4];
    v.x -= l; v.y -= l; v.z -= l; v.w -= l;
    reinterpret_cast<float4*>(out)[i4] = v;
  }
}

// =====================================================================
extern "C" void kernel_launch(void* const* d_in, const int* in_sizes, int n_in,
                              void* d_out, int out_size, void* d_ws, size_t ws_size,
                              hipStream_t stream)
{
  const float* x    = (const float*)d_in[0];
  const int*   ei   = (const int*)  d_in[1];
  const int*   et   = (const int*)  d_in[2];
  const float* Wrel = (const float*)d_in[3];
  const float* W0   = (const float*)d_in[4];
  const float* Wg   = (const float*)d_in[5];
  const float* bg   = (const float*)d_in[6];
  const float* Ws   = (const float*)d_in[7];
  const float* bs   = (const float*)d_in[8];
  float* out = (float*)d_out;

  // ws layout (bytes): Ybf | X0H | P1 | Pg | Ps | LSE | Wttg | Wtts (~60.3 MB)
  char* p = (char*)d_ws;
  unsigned short* Ybf = (unsigned short*)p;  p += (size_t)B_*YLD*2;
  unsigned short* X0H = (unsigned short*)p;  p += (size_t)B_*XLD*2;
  float*  P1  = (float*)p;                   p += (size_t)8*B_*PLD*4;
  float2* Pg  = (float2*)p;                  p += (size_t)NCBG*512*8;
  float2* Ps  = (float2*)p;                  p += (size_t)NCBS*512*8;
  float*  LSE = (float*)p;                   p += 4096;
  unsigned short* Wttg = (unsigned short*)p; p += (size_t)40*CPADG*16;
  unsigned short* Wtts = (unsigned short*)p;

  // W pre-transpose (octet-major bf16)
  wtrans2<<<dim3(CPADG/64, 5), 256, 0, stream>>>(Wg, NG_, CPADG, Wttg);
  wtrans2<<<dim3(CPADS/64, 5), 256, 0, stream>>>(Ws, NS_, CPADS, Wtts);

  k1a_coef_y<<<B_, 256, 0, stream>>>(x, ei, et, Ybf);

  // k1b: P1[z] = Y @ [Wrel;W0] partials (z-split over 33 K-tiles)
  gemm_k1b<<<2*5*8, 256, 0, stream>>>(Ybf, YLD, Wrel, W0, P1, 8);
  k1c_reduce<<<(B_*XLD + 255)/256, 256, 0, stream>>>(P1, 8, X0H);

  // heads: logits (+bias) -> out, per-tile (max,sumexp) -> Pg/Ps
  gemm9<<<256, 512, 0, stream>>>(X0H, Wttg, Wtts, bg, bs, out, Pg, Ps);

  k5b<<<128, 256, 0, stream>>>(Pg, Ps, LSE);
  k4_sub<<<2048, 256, 0, stream>>>(out, LSE);
}